// Round 1
// baseline (2889.066 us; speedup 1.0000x reference)
//
#include <hip/hip_runtime.h>

#define HD 512
#define VOC 10000
#define SL 32
#define BA 256
#define BH (BA*HD)

typedef __bf16 b16x8 __attribute__((ext_vector_type(8)));
typedef float f32x4 __attribute__((ext_vector_type(4)));

__device__ __forceinline__ ushort f2bf(float x) {
  unsigned u = __float_as_uint(x);
  u += 0x7fffu + ((u >> 16) & 1u);
  return (ushort)(u >> 16);
}

// ---------------- fp32 -> bf16 convert ----------------
__global__ __launch_bounds__(256) void cvt_k(const float* __restrict__ in,
                                             ushort* __restrict__ out, int n4) {
  int i = blockIdx.x * 256 + threadIdx.x;
  if (i < n4) {
    float4 v = ((const float4*)in)[i];
    ((ushort4*)out)[i] = make_ushort4(f2bf(v.x), f2bf(v.y), f2bf(v.z), f2bf(v.w));
  }
}

// ---------------- embedding gathers (rows = l*256+b) ----------------
__global__ __launch_bounds__(64) void gather_enc_k(const float* __restrict__ table,
                                                   const int* __restrict__ toks,
                                                   ushort* __restrict__ out) {
  int row = blockIdx.x;            // l*256 + b
  int l = row >> 8, b = row & 255;
  int tok = toks[b * SL + l];
  const float4* src = (const float4*)(table + (size_t)tok * HD);
  int t = threadIdx.x;
  float4 v0 = src[t * 2], v1 = src[t * 2 + 1];
  uint4 o;
  o.x = (unsigned)f2bf(v0.x) | ((unsigned)f2bf(v0.y) << 16);
  o.y = (unsigned)f2bf(v0.z) | ((unsigned)f2bf(v0.w) << 16);
  o.z = (unsigned)f2bf(v1.x) | ((unsigned)f2bf(v1.y) << 16);
  o.w = (unsigned)f2bf(v1.z) | ((unsigned)f2bf(v1.w) << 16);
  *(uint4*)(out + (size_t)row * HD + t * 8) = o;
}

__global__ __launch_bounds__(64) void gather_dec_k(const float* __restrict__ table,
                                                   const int* __restrict__ toks,
                                                   ushort* __restrict__ out) {
  int row = blockIdx.x;
  int l = row >> 8, b = row & 255;
  int tok = (l == 0) ? 1 : toks[b * SL + l - 1];
  const float4* src = (const float4*)(table + (size_t)tok * HD);
  int t = threadIdx.x;
  float4 v0 = src[t * 2], v1 = src[t * 2 + 1];
  uint4 o;
  o.x = (unsigned)f2bf(v0.x) | ((unsigned)f2bf(v0.y) << 16);
  o.y = (unsigned)f2bf(v0.z) | ((unsigned)f2bf(v0.w) << 16);
  o.z = (unsigned)f2bf(v1.x) | ((unsigned)f2bf(v1.y) << 16);
  o.w = (unsigned)f2bf(v1.z) | ((unsigned)f2bf(v1.w) << 16);
  *(uint4*)(out + (size_t)row * HD + t * 8) = o;
}

// ---------------- generic bf16 GEMM: C[m][n] = sum_k A[m][k]*W[n][k] ----------------
// A: [M x 512] bf16 (ld=512). W: bf16 rows, row stride ldw. K fixed = 512.
// Block tile 64x64, 4 waves, each wave 64x16 (4 m-frags).
__global__ __launch_bounds__(256) void gemm_k(
    const ushort* __restrict__ A, const ushort* __restrict__ W,
    int N, int ldw,
    const float* __restrict__ bias, const float* __restrict__ addsrc,
    int relu, float* __restrict__ outf, int ldc, ushort* __restrict__ outbf) {
  __shared__ ushort lsA[4][64][8];
  __shared__ ushort lsB[4][64][8];
  int t = threadIdx.x;
  int lane = t & 63, w = t >> 6;
  int m0 = blockIdx.x * 64, n0 = blockIdx.y * 64;
  f32x4 acc[4] = {};
  int sr = t >> 2, g = t & 3;
  const ushort* Ap = A + (size_t)(m0 + sr) * HD + g * 8;
  int nr = n0 + sr; if (nr > N - 1) nr = N - 1;
  const ushort* Wp = W + (size_t)nr * ldw + g * 8;
  for (int ks = 0; ks < 16; ++ks) {
    *(uint4*)(&lsA[g][sr][0]) = *(const uint4*)(Ap + ks * 32);
    *(uint4*)(&lsB[g][sr][0]) = *(const uint4*)(Wp + ks * 32);
    __syncthreads();
    int gg = lane >> 4, r = lane & 15;
    b16x8 bf = *(const b16x8*)(&lsB[gg][w * 16 + r][0]);
#pragma unroll
    for (int mi = 0; mi < 4; ++mi) {
      b16x8 af = *(const b16x8*)(&lsA[gg][mi * 16 + r][0]);
      acc[mi] = __builtin_amdgcn_mfma_f32_16x16x32_bf16(af, bf, acc[mi], 0, 0, 0);
    }
    __syncthreads();
  }
  int gg = lane >> 4, cl = lane & 15;
  int col = n0 + w * 16 + cl;
  if (col >= N) return;
  float bv = bias ? bias[col] : 0.f;
#pragma unroll
  for (int mi = 0; mi < 4; ++mi) {
#pragma unroll
    for (int r = 0; r < 4; ++r) {
      int row = m0 + mi * 16 + gg * 4 + r;
      float v = acc[mi][r] + bv;
      if (addsrc) v += addsrc[(size_t)row * N + col];
      if (relu) v = fmaxf(v, 0.f);
      if (outf) outf[(size_t)row * ldc + col] = v;
      if (outbf) outbf[(size_t)row * N + col] = f2bf(v);
    }
  }
}

// ---------------- fused GRU step: h2 = GRU(x, h) ----------------
// M=256 rows, j in [0,512). 6 accumulator sets (x·Wih[r,z,n], h·Whh[r,z,n]).
// Block tile 32(m) x 64(j). grid (8,8).
__global__ __launch_bounds__(256) void gru_k(
    const ushort* __restrict__ Xbf, const ushort* __restrict__ Hbf,
    const ushort* __restrict__ Wih, const ushort* __restrict__ Whh,
    const float* __restrict__ b_ih, const float* __restrict__ b_hh,
    const float* __restrict__ Hf32,
    float* __restrict__ Hout_f32, ushort* __restrict__ Hout_bf) {
  __shared__ ushort lsX[4][32][8];
  __shared__ ushort lsH[4][32][8];
  __shared__ ushort lsW[6][4][64][8];
  int t = threadIdx.x, lane = t & 63, w = t >> 6;
  int m0 = blockIdx.x * 32, j0 = blockIdx.y * 64;
  f32x4 acc[2][6] = {};
  int sr = t >> 2, g = t & 3;
  for (int ks = 0; ks < 16; ++ks) {
    int k0 = ks * 32;
    if (t < 128) {
      *(uint4*)(&lsX[g][sr][0]) = *(const uint4*)(Xbf + (size_t)(m0 + sr) * HD + k0 + g * 8);
    } else {
      int sr2 = sr - 32;
      *(uint4*)(&lsH[g][sr2][0]) = *(const uint4*)(Hbf + (size_t)(m0 + sr2) * HD + k0 + g * 8);
    }
#pragma unroll
    for (int s = 0; s < 3; ++s) {
      *(uint4*)(&lsW[s][g][sr][0]) =
          *(const uint4*)(Wih + (size_t)(s * 512 + j0 + sr) * HD + k0 + g * 8);
      *(uint4*)(&lsW[s + 3][g][sr][0]) =
          *(const uint4*)(Whh + (size_t)(s * 512 + j0 + sr) * HD + k0 + g * 8);
    }
    __syncthreads();
    int gg = lane >> 4, r = lane & 15;
    b16x8 bw[6];
#pragma unroll
    for (int s = 0; s < 6; ++s) bw[s] = *(const b16x8*)(&lsW[s][gg][w * 16 + r][0]);
#pragma unroll
    for (int mi = 0; mi < 2; ++mi) {
      b16x8 ax = *(const b16x8*)(&lsX[gg][mi * 16 + r][0]);
      b16x8 ah = *(const b16x8*)(&lsH[gg][mi * 16 + r][0]);
      acc[mi][0] = __builtin_amdgcn_mfma_f32_16x16x32_bf16(ax, bw[0], acc[mi][0], 0, 0, 0);
      acc[mi][1] = __builtin_amdgcn_mfma_f32_16x16x32_bf16(ax, bw[1], acc[mi][1], 0, 0, 0);
      acc[mi][2] = __builtin_amdgcn_mfma_f32_16x16x32_bf16(ax, bw[2], acc[mi][2], 0, 0, 0);
      acc[mi][3] = __builtin_amdgcn_mfma_f32_16x16x32_bf16(ah, bw[3], acc[mi][3], 0, 0, 0);
      acc[mi][4] = __builtin_amdgcn_mfma_f32_16x16x32_bf16(ah, bw[4], acc[mi][4], 0, 0, 0);
      acc[mi][5] = __builtin_amdgcn_mfma_f32_16x16x32_bf16(ah, bw[5], acc[mi][5], 0, 0, 0);
    }
    __syncthreads();
  }
  int gg = lane >> 4, cl = lane & 15;
  int j = j0 + w * 16 + cl;
  float bir = b_ih[j], biz = b_ih[512 + j], bin_ = b_ih[1024 + j];
  float bhr = b_hh[j], bhz = b_hh[512 + j], bhn = b_hh[1024 + j];
#pragma unroll
  for (int mi = 0; mi < 2; ++mi) {
#pragma unroll
    for (int r = 0; r < 4; ++r) {
      int b = m0 + mi * 16 + gg * 4 + r;
      float ir = acc[mi][0][r] + bir, iz = acc[mi][1][r] + biz, inn = acc[mi][2][r] + bin_;
      float hr = acc[mi][3][r] + bhr, hz = acc[mi][4][r] + bhz, hn = acc[mi][5][r] + bhn;
      float rr = 1.f / (1.f + expf(-(ir + hr)));
      float zz = 1.f / (1.f + expf(-(iz + hz)));
      float nn = tanhf(inn + rr * hn);
      float hp = Hf32[(size_t)b * HD + j];
      float h2 = (1.f - zz) * nn + zz * hp;
      Hout_f32[(size_t)b * HD + j] = h2;
      Hout_bf[(size_t)b * HD + j] = f2bf(h2);
    }
  }
}

// ---------------- attention: softmax(h·attn_wh + pre) applied to enc_outs ----------------
// 32 blocks x 256 threads, 8 batch rows per block.
__global__ __launch_bounds__(256) void attn_k(
    const float* __restrict__ h,         // [256][512]
    const float* __restrict__ attn_w,    // [32][1024] fp32 (cols 512.. used)
    const float* __restrict__ attn_pre,  // [256][32] (this step)
    const float* __restrict__ enc_outs,  // [32][256][512]
    ushort* __restrict__ applied_bf) {   // [256][512]
  __shared__ float aw[8][32];
  int t = threadIdx.x;
  int b0 = blockIdx.x * 8;
  int bl = t >> 5, lc = t & 31;
  int b = b0 + bl;
  const float4* hp = (const float4*)(h + (size_t)b * HD);
  const float4* wp = (const float4*)(attn_w + (size_t)lc * 1024 + 512);
  float d = 0.f;
#pragma unroll 4
  for (int i = 0; i < 128; ++i) {
    float4 a = hp[i], c = wp[i];
    d += a.x * c.x + a.y * c.y + a.z * c.z + a.w * c.w;
  }
  d += attn_pre[b * 32 + lc];
  float m = d;
  for (int o = 16; o; o >>= 1) m = fmaxf(m, __shfl_xor(m, o, 32));
  float e = expf(d - m), s = e;
  for (int o = 16; o; o >>= 1) s += __shfl_xor(s, o, 32);
  aw[bl][lc] = e / s;
  __syncthreads();
  int q = t & 31;
  float4 acc4[4] = {};
  for (int ll = 0; ll < 32; ++ll) {
    float a = aw[bl][ll];
    const float4* row = (const float4*)(enc_outs + ((size_t)ll * BA + b) * HD);
#pragma unroll
    for (int i = 0; i < 4; ++i) {
      float4 v = row[q + 32 * i];
      acc4[i].x += a * v.x; acc4[i].y += a * v.y;
      acc4[i].z += a * v.z; acc4[i].w += a * v.w;
    }
  }
  ushort4* ob = (ushort4*)(applied_bf + (size_t)b * HD);
#pragma unroll
  for (int i = 0; i < 4; ++i) {
    ob[q + 32 * i] = make_ushort4(f2bf(acc4[i].x), f2bf(acc4[i].y),
                                  f2bf(acc4[i].z), f2bf(acc4[i].w));
  }
}

// ---------------- log-softmax: pass 1 (per-row logsumexp) ----------------
__global__ __launch_bounds__(256) void lse_k(const float* __restrict__ logits,
                                             float* __restrict__ z) {
  __shared__ float red[4];
  int row = blockIdx.x, t = threadIdx.x;
  const float4* p = (const float4*)(logits + (size_t)row * VOC);
  float m = -1e30f;
  for (int i = t; i < 2500; i += 256) {
    float4 v = p[i];
    m = fmaxf(fmaxf(m, fmaxf(v.x, v.y)), fmaxf(v.z, v.w));
  }
  for (int o = 32; o; o >>= 1) m = fmaxf(m, __shfl_xor(m, o, 64));
  if ((t & 63) == 0) red[t >> 6] = m;
  __syncthreads();
  m = fmaxf(fmaxf(red[0], red[1]), fmaxf(red[2], red[3]));
  __syncthreads();
  float s = 0.f;
  for (int i = t; i < 2500; i += 256) {
    float4 v = p[i];
    s += expf(v.x - m) + expf(v.y - m) + expf(v.z - m) + expf(v.w - m);
  }
  for (int o = 32; o; o >>= 1) s += __shfl_xor(s, o, 64);
  if ((t & 63) == 0) red[t >> 6] = s;
  __syncthreads();
  if (t == 0) z[row] = m + logf(red[0] + red[1] + red[2] + red[3]);
}

// ---------------- log-softmax: pass 2 (subtract) ----------------
__global__ __launch_bounds__(256) void sub_k(float* __restrict__ logits,
                                             const float* __restrict__ z) {
  int row = blockIdx.y;
  int i = blockIdx.x * 256 + threadIdx.x;
  if (i < 2500) {
    float4* p = (float4*)(logits + (size_t)row * VOC);
    float zv = z[row];
    float4 v = p[i];
    v.x -= zv; v.y -= zv; v.z -= zv; v.w -= zv;
    p[i] = v;
  }
}

extern "C" void kernel_launch(void* const* d_in, const int* in_sizes, int n_in,
                              void* d_out, int out_size, void* d_ws, size_t ws_size,
                              hipStream_t stream) {
  (void)in_sizes; (void)n_in; (void)out_size; (void)ws_size;
  const int* in_tok = (const int*)d_in[0];
  const int* tgt_tok = (const int*)d_in[1];
  const float* enc_embed = (const float*)d_in[2];
  const float* enc_w_ih = (const float*)d_in[3];
  const float* enc_w_hh = (const float*)d_in[4];
  const float* enc_b_ih = (const float*)d_in[5];
  const float* enc_b_hh = (const float*)d_in[6];
  const float* dec_embed = (const float*)d_in[7];
  const float* attn_w = (const float*)d_in[8];
  const float* attn_b = (const float*)d_in[9];
  const float* comb_w = (const float*)d_in[10];
  const float* comb_b = (const float*)d_in[11];
  const float* dec_w_ih = (const float*)d_in[12];
  const float* dec_w_hh = (const float*)d_in[13];
  const float* dec_b_ih = (const float*)d_in[14];
  const float* dec_b_hh = (const float*)d_in[15];
  const float* out_w = (const float*)d_in[16];
  const float* out_b = (const float*)d_in[17];
  float* out = (float*)d_out;

  char* ws = (char*)d_ws;
  size_t off = 0;
  auto carve = [&](size_t bytes) {
    void* p = ws + off;
    off += (bytes + 255) & ~(size_t)255;
    return p;
  };
  ushort* enc_wih_bf = (ushort*)carve(1536 * 512 * 2);
  ushort* enc_whh_bf = (ushort*)carve(1536 * 512 * 2);
  ushort* dec_wih_bf = (ushort*)carve(1536 * 512 * 2);
  ushort* dec_whh_bf = (ushort*)carve(1536 * 512 * 2);
  ushort* comb_w_bf  = (ushort*)carve(512 * 1024 * 2);
  ushort* attn_w_bf  = (ushort*)carve(32 * 1024 * 2);
  ushort* out_w_bf   = (ushort*)carve((size_t)VOC * HD * 2);
  ushort* enc_emb_bf = (ushort*)carve((size_t)SL * BA * HD * 2);
  ushort* dec_emb_bf = (ushort*)carve((size_t)SL * BA * HD * 2);
  float* attn_pre    = (float*)carve((size_t)SL * BA * 32 * 4);
  float* comb_pre    = (float*)carve((size_t)SL * BA * HD * 4);
  float* enc_outs    = (float*)carve((size_t)SL * BA * HD * 4);
  ushort* H2_bf      = (ushort*)carve((size_t)SL * BA * HD * 2);
  ushort* hbf0       = (ushort*)carve(BH * 2);
  ushort* hbf1       = (ushort*)carve(BH * 2);
  float* hzero       = (float*)carve(BH * 4);
  float* hdec0       = (float*)carve(BH * 4);
  float* hdec1       = (float*)carve(BH * 4);
  ushort* applied_bf = (ushort*)carve(BH * 2);
  ushort* x_bf       = (ushort*)carve(BH * 2);
  float* zbuf        = (float*)carve(SL * BA * 4);

  // ---- setup: converts, gathers, zero h ----
  cvt_k<<<768, 256, 0, stream>>>(enc_w_ih, enc_wih_bf, 1536 * 512 / 4);
  cvt_k<<<768, 256, 0, stream>>>(enc_w_hh, enc_whh_bf, 1536 * 512 / 4);
  cvt_k<<<768, 256, 0, stream>>>(dec_w_ih, dec_wih_bf, 1536 * 512 / 4);
  cvt_k<<<768, 256, 0, stream>>>(dec_w_hh, dec_whh_bf, 1536 * 512 / 4);
  cvt_k<<<512, 256, 0, stream>>>(comb_w, comb_w_bf, 512 * 1024 / 4);
  cvt_k<<<32, 256, 0, stream>>>(attn_w, attn_w_bf, 32 * 1024 / 4);
  cvt_k<<<5000, 256, 0, stream>>>(out_w, out_w_bf, VOC * HD / 4);
  gather_enc_k<<<SL * BA, 64, 0, stream>>>(enc_embed, in_tok, enc_emb_bf);
  gather_dec_k<<<SL * BA, 64, 0, stream>>>(dec_embed, tgt_tok, dec_emb_bf);
  hipMemsetAsync(hbf0, 0, BH * 2, stream);
  hipMemsetAsync(hzero, 0, BH * 4, stream);

  // ---- decoder embedding-dependent precomputes ----
  // attn_pre = dec_emb @ attn_w[:, :512].T + attn_b   -> [8192 x 32]
  gemm_k<<<dim3(128, 1), 256, 0, stream>>>(dec_emb_bf, attn_w_bf, 32, 1024,
                                           attn_b, nullptr, 0, attn_pre, 32, nullptr);
  // comb_pre = dec_emb @ comb_w[:, :512].T + comb_b   -> [8192 x 512]
  gemm_k<<<dim3(128, 8), 256, 0, stream>>>(dec_emb_bf, comb_w_bf, 512, 1024,
                                           comb_b, nullptr, 0, comb_pre, 512, nullptr);

  // ---- encoder: 32 GRU steps ----
  for (int l = 0; l < SL; ++l) {
    const ushort* hbf_in = (l & 1) ? hbf1 : hbf0;
    ushort* hbf_out = (l & 1) ? hbf0 : hbf1;
    const float* hf_in = (l == 0) ? hzero : (enc_outs + (size_t)(l - 1) * BH);
    gru_k<<<dim3(8, 8), 256, 0, stream>>>(enc_emb_bf + (size_t)l * BH, hbf_in,
                                          enc_wih_bf, enc_whh_bf, enc_b_ih, enc_b_hh,
                                          hf_in, enc_outs + (size_t)l * BH, hbf_out);
  }

  // ---- decoder: 32 steps (attn -> comb GEMM -> GRU) ----
  for (int l = 0; l < SL; ++l) {
    const ushort* hbf_in = (l == 0) ? hbf0 : (H2_bf + (size_t)(l - 1) * BH);
    const float* hf_in = (l == 0) ? (enc_outs + (size_t)31 * BH)
                                  : ((l & 1) ? hdec0 : hdec1);
    float* hf_out = (l & 1) ? hdec1 : hdec0;
    attn_k<<<32, 256, 0, stream>>>(hf_in, attn_w, attn_pre + (size_t)l * BA * 32,
                                   enc_outs, applied_bf);
    gemm_k<<<dim3(4, 8), 256, 0, stream>>>(applied_bf, comb_w_bf + 512, 512, 1024,
                                           nullptr, comb_pre + (size_t)l * BH, 1,
                                           nullptr, 0, x_bf);
    gru_k<<<dim3(8, 8), 256, 0, stream>>>(x_bf, hbf_in, dec_wih_bf, dec_whh_bf,
                                          dec_b_ih, dec_b_hh, hf_in, hf_out,
                                          H2_bf + (size_t)l * BH);
  }

  // ---- output projection + log_softmax ----
  gemm_k<<<dim3(128, 157), 256, 0, stream>>>(H2_bf, out_w_bf, VOC, HD,
                                             out_b, nullptr, 0, out, VOC, nullptr);
  lse_k<<<SL * BA, 256, 0, stream>>>(out, zbuf);
  sub_k<<<dim3(10, SL * BA), 256, 0, stream>>>(out, zbuf);
}